// Round 4
// baseline (726.191 us; speedup 1.0000x reference)
//
#include <hip/hip_runtime.h>
#include <hip/hip_bf16.h>

// GCN 3-layer forward, fp32 (bf16 gather features), MI355X.
// Round 4:
//  (a) XCD-private CSR regions: per-replica counts scanned REPLICA-MAJOR, so
//      replica r (blocks ≡ r mod 8 ~ XCD r) writes a contiguous ~E/8 slice of
//      csr -> single-owner L2-resident dirty lines (r3: 98.7MB writeback for
//      12.8MB data). Gather walks 8 short segments per node.
//  (b) GEMM without LDS: W read from global (L1/L2-temporal broadcast),
//      removing the 64KiB LDS stage that capped occupancy at 18%.
//
// Pipeline (all recomputed every call => graph-replay safe):
//  1. memset hist; k_edge_pass1R: hist[r*N+dst] += (1<<40) + attr*2^32
//  2. k_degcnt: dinv = rsqrt(1 + sum_r w)
//  3. scanA/scanB_big/scanC over the 8N count array (r-major) -> ptr, cursor
//  4. k_fill: pos = atomicAdd(cursor[r*N+dst]) (XCD-local), csr[pos]={src,w}
//  5. gemm1(bf16 out) -> gather1 -> BN1 -> gemm2(BN fused) -> gather2 -> BN2
//     -> dotW3 -> gather3(out)

#define HID 128
#define BN_EPS 1e-5f

static inline size_t alignup(size_t x){ return (x + 255) & ~(size_t)255; }

// hist[r*N + dst] += (1<<40) + round(attr * 2^32); r = blockIdx&7 ~ XCD id.
__global__ void k_edge_pass1R(const int* __restrict__ ei, const float* __restrict__ attr,
                              unsigned long long* __restrict__ hist, int N, int E){
  int e = blockIdx.x*256 + threadIdx.x;
  if (e >= E) return;
  int r = blockIdx.x & 7;
  int dst = ei[E + e];
  unsigned long long pk = (1ULL << 40)
                        + (unsigned long long)((double)attr[e] * 4294967296.0);
  atomicAdd(&hist[(size_t)r*N + dst], pk);
}

// dinv[i] = 1/sqrt(1 + sum_r weight)
__global__ void k_degcnt(const unsigned long long* __restrict__ hist,
                         float* __restrict__ dinv, int N){
  int i = blockIdx.x*256 + threadIdx.x;
  if (i >= N) return;
  unsigned long long wsum = 0;
  #pragma unroll
  for (int r = 0; r < 8; ++r)
    wsum += hist[(size_t)r*N + i] & ((1ULL << 40) - 1);
  float deg = 1.0f + (float)((double)wsum * 2.3283064365386963e-10);  // *2^-32
  dinv[i] = 1.0f / sqrtf(deg);   // deg >= 1 always (self loop)
}

// exclusive scan over the flattened 8N count array (counts from hist>>40)
__global__ void k_scanA(const unsigned long long* __restrict__ hist,
                        int* ptr, int* bsum, int n8){
  __shared__ int tmp[256];
  int i = blockIdx.x*256 + threadIdx.x;
  int v = (i < n8) ? (int)(hist[i] >> 40) : 0;
  tmp[threadIdx.x] = v;
  __syncthreads();
  #pragma unroll
  for (int d = 1; d < 256; d <<= 1){
    int t = (threadIdx.x >= d) ? tmp[threadIdx.x - d] : 0;
    __syncthreads();
    tmp[threadIdx.x] += t;
    __syncthreads();
  }
  if (i < n8) ptr[i] = tmp[threadIdx.x] - v;      // exclusive within block
  if (threadIdx.x == 255) bsum[blockIdx.x] = tmp[255];
}

// single-block sequential-chunk exclusive scan of nb block sums (nb up to ~4k)
__global__ void k_scanB_big(int* bsum, int nb){
  __shared__ int tmp[512];
  __shared__ int carry;
  if (threadIdx.x == 0) carry = 0;
  __syncthreads();
  for (int base = 0; base < nb; base += 512){
    int idx = base + threadIdx.x;
    int v = (idx < nb) ? bsum[idx] : 0;
    tmp[threadIdx.x] = v;
    __syncthreads();
    #pragma unroll
    for (int d = 1; d < 512; d <<= 1){
      int t = (threadIdx.x >= d) ? tmp[threadIdx.x - d] : 0;
      __syncthreads();
      tmp[threadIdx.x] += t;
      __syncthreads();
    }
    int total = tmp[511];
    if (idx < nb) bsum[idx] = tmp[threadIdx.x] - v + carry;
    __syncthreads();
    if (threadIdx.x == 0) carry += total;
    __syncthreads();
  }
}

__global__ void k_scanC(int* ptr, int* cursor, const int* __restrict__ bsum,
                        int n8, int E){
  int i = blockIdx.x*256 + threadIdx.x;
  if (i < n8){
    int v = ptr[i] + bsum[blockIdx.x];
    ptr[i] = v;
    cursor[i] = v;
  }
  if (i == 0) ptr[n8] = E;   // sentinel: end of last segment
}

__global__ void k_fill(const int* __restrict__ ei, const float* __restrict__ attr,
                       const float* __restrict__ dinv, int* __restrict__ cursor,
                       int2* __restrict__ csr, int N, int E){
  int e = blockIdx.x*256 + threadIdx.x;
  if (e >= E) return;
  int r = blockIdx.x & 7;
  int src = ei[e];
  int dst = ei[E + e];
  int pos = atomicAdd(&cursor[(size_t)r*N + dst], 1);
  float w = dinv[src] * attr[e] * dinv[dst];
  csr[pos] = make_int2(src, __float_as_int(w));
}

// C[n,128](bf16 pairs) = act(A[n,128]) @ W[128,128]; act = BN(scale,shift)+ReLU.
// 256 threads = 8 row-groups x 32 col-groups; 32 rows/block, 4x4 per thread.
// W read straight from global (64KB, L1/L2-temporal; lanes with same cg across
// row-groups broadcast) -- no LDS, no barrier, occupancy VGPR-bound.
#define BNAPP(v) do{ if (BN){ \
  v.x = fmaxf(fmaf(v.x, sc.x, sh.x), 0.f); \
  v.y = fmaxf(fmaf(v.y, sc.y, sh.y), 0.f); \
  v.z = fmaxf(fmaf(v.z, sc.z, sh.z), 0.f); \
  v.w = fmaxf(fmaf(v.w, sc.w, sh.w), 0.f); } }while(0)

#define GSTEP(KK, COMP) { \
  float4 wv = *(const float4*)(Wg + (size_t)(k0+KK)*128 + cg*4); \
  acc0.x = fmaf(av0.COMP, wv.x, acc0.x); acc0.y = fmaf(av0.COMP, wv.y, acc0.y); \
  acc0.z = fmaf(av0.COMP, wv.z, acc0.z); acc0.w = fmaf(av0.COMP, wv.w, acc0.w); \
  acc1.x = fmaf(av1.COMP, wv.x, acc1.x); acc1.y = fmaf(av1.COMP, wv.y, acc1.y); \
  acc1.z = fmaf(av1.COMP, wv.z, acc1.z); acc1.w = fmaf(av1.COMP, wv.w, acc1.w); \
  acc2.x = fmaf(av2.COMP, wv.x, acc2.x); acc2.y = fmaf(av2.COMP, wv.y, acc2.y); \
  acc2.z = fmaf(av2.COMP, wv.z, acc2.z); acc2.w = fmaf(av2.COMP, wv.w, acc2.w); \
  acc3.x = fmaf(av3.COMP, wv.x, acc3.x); acc3.y = fmaf(av3.COMP, wv.y, acc3.y); \
  acc3.z = fmaf(av3.COMP, wv.z, acc3.z); acc3.w = fmaf(av3.COMP, wv.w, acc3.w); }

static __device__ inline uint2 pack_bf16x4(float4 a){
  __hip_bfloat162 lo = __float22bfloat162_rn({a.x, a.y});
  __hip_bfloat162 hi = __float22bfloat162_rn({a.z, a.w});
  uint2 r;
  r.x = *(unsigned int*)&lo;
  r.y = *(unsigned int*)&hi;
  return r;
}

template<bool BN>
__global__ __launch_bounds__(256) void k_gemm128(const float* __restrict__ A,
    const float* __restrict__ Wg, const float* __restrict__ coef,
    unsigned int* __restrict__ C, int n){   // C: bf16 pairs, 64 per row
  int cg = threadIdx.x & 31;
  int rg = threadIdx.x >> 5;
  int row0 = blockIdx.x*32 + rg*4;
  if (row0 >= n) return;
  float4 acc0 = {0,0,0,0}, acc1 = {0,0,0,0}, acc2 = {0,0,0,0}, acc3 = {0,0,0,0};
  const float* a0 = A + (size_t)row0 * HID;
  #pragma unroll 4
  for (int k0 = 0; k0 < 128; k0 += 4){
    float4 sc = {0,0,0,0}, sh = {0,0,0,0};
    if (BN){ sc = *(const float4*)(coef + k0); sh = *(const float4*)(coef + 128 + k0); }
    float4 av0 = *(const float4*)(a0 + 0*HID + k0);
    float4 av1 = *(const float4*)(a0 + 1*HID + k0);
    float4 av2 = *(const float4*)(a0 + 2*HID + k0);
    float4 av3 = *(const float4*)(a0 + 3*HID + k0);
    BNAPP(av0); BNAPP(av1); BNAPP(av2); BNAPP(av3);
    GSTEP(0, x) GSTEP(1, y) GSTEP(2, z) GSTEP(3, w)
  }
  *(uint2*)(C + (size_t)(row0+0)*64 + cg*2) = pack_bf16x4(acc0);
  *(uint2*)(C + (size_t)(row0+1)*64 + cg*2) = pack_bf16x4(acc1);
  *(uint2*)(C + (size_t)(row0+2)*64 + cg*2) = pack_bf16x4(acc2);
  *(uint2*)(C + (size_t)(row0+3)*64 + cg*2) = pack_bf16x4(acc3);
}

static __device__ inline float2 bf16pair(unsigned int u){
  __hip_bfloat162 h = *(__hip_bfloat162*)&u;
  return __bfloat1622float2(h);
}

// out[node][:] = bias + dinv^2 * xw[node][:] + sum over 8 replica segments.
// One wave per node, 2 bf16 channels per lane. Segment descriptors batched
// into registers up-front so their load latencies overlap.
__global__ __launch_bounds__(256) void k_gather128(const unsigned int* __restrict__ xwb,
    const int2* __restrict__ csr, const int* __restrict__ ptr,
    const float* __restrict__ dinv, const float* __restrict__ bias,
    float* __restrict__ out, int n, int N){
  int node = blockIdx.x*4 + (threadIdx.x >> 6);
  int lane = threadIdx.x & 63;
  if (node >= n) return;
  int segs[8], sege[8];
  #pragma unroll
  for (int r = 0; r < 8; ++r){
    segs[r] = ptr[(size_t)r*N + node];
    sege[r] = ptr[(size_t)r*N + node + 1];
  }
  float di = dinv[node];
  float2 b = *(const float2*)(bias + lane*2);
  float2 self = bf16pair(xwb[(size_t)node*64 + lane]);
  float sw = di * di;
  float accx = fmaf(sw, self.x, b.x);
  float accy = fmaf(sw, self.y, b.y);
  #pragma unroll
  for (int r = 0; r < 8; ++r){
    int j = segs[r], end = sege[r];
    for (; j + 2 <= end; j += 2){
      int2 ea = csr[j], eb = csr[j+1];
      float2 va = bf16pair(xwb[(size_t)ea.x*64 + lane]);
      float2 vb = bf16pair(xwb[(size_t)eb.x*64 + lane]);
      float wa = __int_as_float(ea.y), wb = __int_as_float(eb.y);
      accx = fmaf(wa, va.x, accx); accy = fmaf(wa, va.y, accy);
      accx = fmaf(wb, vb.x, accx); accy = fmaf(wb, vb.y, accy);
    }
    if (j < end){
      int2 ea = csr[j];
      float2 va = bf16pair(xwb[(size_t)ea.x*64 + lane]);
      float wa = __int_as_float(ea.y);
      accx = fmaf(wa, va.x, accx); accy = fmaf(wa, va.y, accy);
    }
  }
  float2 r2; r2.x = accx; r2.y = accy;
  *(float2*)(out + (size_t)node*HID + lane*2) = r2;
}

__global__ __launch_bounds__(256) void k_bnstats(const float* __restrict__ h,
                                                 float* stats, int n){
  __shared__ float ls[256], lq[256];
  int c = threadIdx.x & 127;
  int r0 = blockIdx.x*2 + (threadIdx.x >> 7);
  float s = 0.f, q = 0.f;
  for (int r = r0; r < n; r += gridDim.x*2){
    float v = h[(size_t)r*HID + c];
    s += v;
    q = fmaf(v, v, q);
  }
  ls[threadIdx.x] = s; lq[threadIdx.x] = q;
  __syncthreads();
  if (threadIdx.x < 128){
    s = ls[threadIdx.x] + ls[threadIdx.x + 128];
    q = lq[threadIdx.x] + lq[threadIdx.x + 128];
    atomicAdd(&stats[c], s);
    atomicAdd(&stats[128 + c], q);
  }
}

__global__ void k_bnfin(const float* __restrict__ stats, const float* __restrict__ gamma,
                        const float* __restrict__ beta, float* coef, int n){
  int c = threadIdx.x;  // 128 threads
  float inv_n = 1.0f / (float)n;
  float mean = stats[c] * inv_n;
  float var = fmaxf(stats[128 + c] * inv_n - mean*mean, 0.f);
  float sc = gamma[c] / sqrtf(var + BN_EPS);
  coef[c] = sc;
  coef[128 + c] = fmaf(-mean, sc, beta[c]);
}

// xw3[row] = sum_c relu(bn2(h[row][c])) * W3[c];  32 lanes per row, float4 each.
__global__ __launch_bounds__(256) void k_dotW3(const float* __restrict__ h,
    const float* __restrict__ coef, const float* __restrict__ W3,
    float* __restrict__ xw3, int n){
  int lane = threadIdx.x & 31;
  int row = blockIdx.x*8 + (threadIdx.x >> 5);
  if (row >= n) return;
  float4 v  = *(const float4*)(h + (size_t)row*HID + lane*4);
  float4 sc = *(const float4*)(coef + lane*4);
  float4 sh = *(const float4*)(coef + 128 + lane*4);
  float4 w  = *(const float4*)(W3 + lane*4);
  float acc = fmaxf(fmaf(v.x, sc.x, sh.x), 0.f) * w.x
            + fmaxf(fmaf(v.y, sc.y, sh.y), 0.f) * w.y
            + fmaxf(fmaf(v.z, sc.z, sh.z), 0.f) * w.z
            + fmaxf(fmaf(v.w, sc.w, sh.w), 0.f) * w.w;
  #pragma unroll
  for (int m = 1; m < 32; m <<= 1) acc += __shfl_xor(acc, m, 32);
  if (lane == 0) xw3[row] = acc;
}

__global__ void k_gather1(const float* __restrict__ xw3, const int2* __restrict__ csr,
    const int* __restrict__ ptr, const float* __restrict__ dinv,
    const float* __restrict__ b3, float* __restrict__ out, int n, int N){
  int i = blockIdx.x*256 + threadIdx.x;
  if (i >= n) return;
  float di = dinv[i];
  float acc = fmaf(di*di, xw3[i], b3[0]);
  #pragma unroll
  for (int r = 0; r < 8; ++r){
    int j = ptr[(size_t)r*N + i];
    int end = ptr[(size_t)r*N + i + 1];
    for (; j < end; ++j){
      int2 e = csr[j];
      acc = fmaf(__int_as_float(e.y), xw3[e.x], acc);
    }
  }
  out[i] = acc;
}

extern "C" void kernel_launch(void* const* d_in, const int* in_sizes, int n_in,
                              void* d_out, int out_size, void* d_ws, size_t ws_size,
                              hipStream_t stream){
  const float* x    = (const float*)d_in[0];
  const int*   ei   = (const int*)  d_in[1];
  const float* attr = (const float*)d_in[2];
  const float* W1   = (const float*)d_in[3];
  const float* b1   = (const float*)d_in[4];
  const float* g1   = (const float*)d_in[5];
  const float* be1  = (const float*)d_in[6];
  const float* W2   = (const float*)d_in[7];
  const float* b2   = (const float*)d_in[8];
  const float* g2   = (const float*)d_in[9];
  const float* be2  = (const float*)d_in[10];
  const float* W3   = (const float*)d_in[11];
  const float* b3   = (const float*)d_in[12];
  float* out = (float*)d_out;

  const int N = in_sizes[0] / HID;   // 100000
  const int E = in_sizes[2];         // 1600000
  const int N8 = 8*N;

  char* w = (char*)d_ws;
  auto take = [&](size_t bytes) -> char* { char* p = w; w += alignup(bytes); return p; };
  unsigned long long* hist = (unsigned long long*)take((size_t)N8*8);
  int*   ptr    = (int*)  take(((size_t)N8+1)*4);
  int*   cursor = (int*)  take((size_t)N8*4);
  float* dinv   = (float*)take((size_t)N*4);
  int*   bsum   = (int*)  take(4096*4);
  float* stats  = (float*)take(256*4);
  float* coef1  = (float*)take(256*4);
  float* coef2  = (float*)take(256*4);
  int2*  csr    = (int2*) take((size_t)E*8);
  float* xw3    = (float*)take((size_t)N*4);
  unsigned int* bufA = (unsigned int*)take((size_t)N*64*4);  // bf16 pairs [N,64]
  float* bufB   = (float*)take((size_t)N*HID*4);
  (void)ws_size; (void)n_in; (void)out_size;

  int nbN  = (N + 255)/256;    // 391
  int nbE  = (E + 255)/256;    // 6250
  int nbN8 = (N8 + 255)/256;   // 3125

  // graph preprocessing
  hipMemsetAsync(hist, 0, (size_t)N8*8, stream);
  k_edge_pass1R <<<nbE,  256, 0, stream>>>(ei, attr, hist, N, E);
  k_degcnt      <<<nbN,  256, 0, stream>>>(hist, dinv, N);
  k_scanA       <<<nbN8, 256, 0, stream>>>(hist, ptr, bsum, N8);
  k_scanB_big   <<<1,    512, 0, stream>>>(bsum, nbN8);
  k_scanC       <<<nbN8, 256, 0, stream>>>(ptr, cursor, bsum, N8, E);
  k_fill        <<<nbE,  256, 0, stream>>>(ei, attr, dinv, cursor, csr, N, E);

  // layer 1
  k_gemm128<false><<<(N+31)/32, 256, 0, stream>>>(x, W1, nullptr, bufA, N);
  k_gather128     <<<(N+3)/4,  256, 0, stream>>>(bufA, csr, ptr, dinv, b1, bufB, N, N);
  hipMemsetAsync(stats, 0, 256*4, stream);
  k_bnstats       <<<512, 256, 0, stream>>>(bufB, stats, N);
  k_bnfin         <<<1, 128, 0, stream>>>(stats, g1, be1, coef1, N);

  // layer 2 (BN1+ReLU fused into gemm A-load)
  k_gemm128<true> <<<(N+31)/32, 256, 0, stream>>>(bufB, W2, coef1, bufA, N);
  k_gather128     <<<(N+3)/4,  256, 0, stream>>>(bufA, csr, ptr, dinv, b2, bufB, N, N);
  hipMemsetAsync(stats, 0, 256*4, stream);
  k_bnstats       <<<512, 256, 0, stream>>>(bufB, stats, N);
  k_bnfin         <<<1, 128, 0, stream>>>(stats, g2, be2, coef2, N);

  // layer 3 (BN2+ReLU fused into the 128->1 dot)
  k_dotW3         <<<(N+7)/8, 256, 0, stream>>>(bufB, coef2, W3, xw3, N);
  k_gather1       <<<nbN, 256, 0, stream>>>(xw3, csr, ptr, dinv, b3, out, N, N);
}

// Round 5
// 475.859 us; speedup vs baseline: 1.5261x; 1.5261x over previous
//
#include <hip/hip_runtime.h>
#include <hip/hip_bf16.h>

// GCN 3-layer forward, MI355X. Round 5:
//  - REVERT r4's replica-major CSR (gather lost its MLP: 88->125us). Back to
//    node-major CSR with per-replica cursors inside each node's block
//    (XCD-local fill atomics, r3 layout).
//  - NEW: GEMMs via bf16 MFMA (16x16x32). W transposed+XOR-swizzled in LDS
//    (32KB), A built from fp32 global with BN+ReLU fused pre-conversion,
//    C written as bf16 pairs (shfl_xor lane-pairing) = gather's input format.
//
// Pipeline (recomputed every call => graph-replay safe):
//  1. memset hist; k_edge_pass1R: hist[r*N+dst] += (1<<40)+attr*2^32 (r=blk&7)
//  2. k_degcnt: dinv = rsqrt(1+sum_r w); cnt = sum_r c
//  3. scanA/scanB/scanC_cursor: rowptr=exscan(cnt); cursorR[r][i]=rowptr[i]+
//     prefix_r
//  4. k_fill: pos=atomicAdd(cursorR[r][dst]) (XCD-local), csr[pos]={src,w}
//  5. mfma gemm1 -> gather1 -> BN1 -> mfma gemm2(BN fused) -> gather2 -> BN2
//     -> dotW3 -> gather3(out)

#define HID 128
#define BN_EPS 1e-5f

typedef __attribute__((ext_vector_type(8))) short bf16x8;
typedef __attribute__((ext_vector_type(4))) float f32x4;

static inline size_t alignup(size_t x){ return (x + 255) & ~(size_t)255; }

// ---------------- graph preprocessing ----------------

__global__ void k_edge_pass1R(const int* __restrict__ ei, const float* __restrict__ attr,
                              unsigned long long* __restrict__ hist, int N, int E){
  int e = blockIdx.x*256 + threadIdx.x;
  if (e >= E) return;
  int r = blockIdx.x & 7;
  int dst = ei[E + e];
  unsigned long long pk = (1ULL << 40)
                        + (unsigned long long)((double)attr[e] * 4294967296.0);
  atomicAdd(&hist[(size_t)r*N + dst], pk);
}

__global__ void k_degcnt(const unsigned long long* __restrict__ hist,
                         float* __restrict__ dinv, int* __restrict__ cnt, int N){
  int i = blockIdx.x*256 + threadIdx.x;
  if (i >= N) return;
  unsigned long long wsum = 0; int c = 0;
  #pragma unroll
  for (int r = 0; r < 8; ++r){
    unsigned long long h = hist[(size_t)r*N + i];
    wsum += h & ((1ULL << 40) - 1);
    c += (int)(h >> 40);
  }
  float deg = 1.0f + (float)((double)wsum * 2.3283064365386963e-10);  // *2^-32
  dinv[i] = 1.0f / sqrtf(deg);
  cnt[i] = c;
}

__global__ void k_scanA(const int* __restrict__ cnt, int* rowptr, int* bsum, int n){
  __shared__ int tmp[256];
  int i = blockIdx.x*256 + threadIdx.x;
  int v = (i < n) ? cnt[i] : 0;
  tmp[threadIdx.x] = v;
  __syncthreads();
  #pragma unroll
  for (int d = 1; d < 256; d <<= 1){
    int t = (threadIdx.x >= d) ? tmp[threadIdx.x - d] : 0;
    __syncthreads();
    tmp[threadIdx.x] += t;
    __syncthreads();
  }
  if (i < n) rowptr[i] = tmp[threadIdx.x] - v;
  if (threadIdx.x == 255) bsum[blockIdx.x] = tmp[255];
}

__global__ void k_scanB(int* bsum, int nb){
  __shared__ int tmp[512];
  int v = (threadIdx.x < nb) ? bsum[threadIdx.x] : 0;
  tmp[threadIdx.x] = v;
  __syncthreads();
  #pragma unroll
  for (int d = 1; d < 512; d <<= 1){
    int t = (threadIdx.x >= d) ? tmp[threadIdx.x - d] : 0;
    __syncthreads();
    tmp[threadIdx.x] += t;
    __syncthreads();
  }
  if (threadIdx.x < nb) bsum[threadIdx.x] = tmp[threadIdx.x] - v;
}

__global__ void k_scanC_cursor(int* rowptr, const int* __restrict__ bsum,
                               const unsigned long long* __restrict__ hist,
                               int* __restrict__ cursorR, int N){
  int i = blockIdx.x*256 + threadIdx.x;
  if (i >= N) return;
  int v = rowptr[i] + bsum[blockIdx.x];
  rowptr[i] = v;
  int running = v;
  #pragma unroll
  for (int r = 0; r < 8; ++r){
    cursorR[(size_t)r*N + i] = running;
    running += (int)(hist[(size_t)r*N + i] >> 40);
  }
}

__global__ void k_fill(const int* __restrict__ ei, const float* __restrict__ attr,
                       const float* __restrict__ dinv, int* __restrict__ cursorR,
                       int2* __restrict__ csr, int N, int E){
  int e = blockIdx.x*256 + threadIdx.x;
  if (e >= E) return;
  int r = blockIdx.x & 7;
  int src = ei[e];
  int dst = ei[E + e];
  int pos = atomicAdd(&cursorR[(size_t)r*N + dst], 1);
  float w = dinv[src] * attr[e] * dinv[dst];
  csr[pos] = make_int2(src, __float_as_int(w));
}

// ---------------- MFMA GEMM ----------------

static __device__ inline uint2 pack_bf16x4(float4 a){
  __hip_bfloat162 lo = __float22bfloat162_rn({a.x, a.y});
  __hip_bfloat162 hi = __float22bfloat162_rn({a.z, a.w});
  uint2 r;
  r.x = *(unsigned int*)&lo;
  r.y = *(unsigned int*)&hi;
  return r;
}

static __device__ inline unsigned short bfbits(float v){
  __hip_bfloat16 h = __float2bfloat16(v);
  return *(unsigned short*)&h;
}

// C[n,128](bf16 pairs) = act(A[n,128]) @ W[128,128]; act = BN+ReLU if BN.
// 256 thr = 4 waves; block does 128 rows (each wave 2 row-tiles of 16).
// W staged in LDS transposed (WT[col][k], bf16) with elem-XOR swizzle
// (k ^ ((col&7)<<3)) so the 16-lane column-slice ds_read_b128 is ~2-way.
template<bool BN>
__global__ __launch_bounds__(256) void k_gemm_mfma(const float* __restrict__ A,
    const float* __restrict__ Wg, const float* __restrict__ coef,
    unsigned int* __restrict__ C, int n){
  __shared__ unsigned short WT[128*128];   // 32 KB
  #pragma unroll
  for (int it = 0; it < 16; ++it){
    int idx = threadIdx.x + 256*it;        // 0..4095 float4s of W
    int k  = idx >> 5;
    int n0 = (idx & 31) * 4;
    float4 wv = *(const float4*)(Wg + (size_t)k*128 + n0);
    unsigned short bb[4] = {bfbits(wv.x), bfbits(wv.y), bfbits(wv.z), bfbits(wv.w)};
    #pragma unroll
    for (int i = 0; i < 4; ++i){
      int col = n0 + i;
      WT[col*128 + (k ^ ((col&7)<<3))] = bb[i];
    }
  }
  __syncthreads();

  int lane = threadIdx.x & 63;
  int wv4  = threadIdx.x >> 6;      // wave 0..3
  int l16  = lane & 15;
  int kg   = lane >> 4;             // 0..3
  int row_base = blockIdx.x*128 + wv4*32;
  int nm1 = n - 1;
  int a0row = min(row_base + l16,      nm1);
  int a1row = min(row_base + 16 + l16, nm1);

  f32x4 acc[2][8] = {};
  #pragma unroll
  for (int k0 = 0; k0 < 128; k0 += 32){
    int k = k0 + kg*8;
    float4 lo0 = *(const float4*)(A + (size_t)a0row*HID + k);
    float4 hi0 = *(const float4*)(A + (size_t)a0row*HID + k + 4);
    float4 lo1 = *(const float4*)(A + (size_t)a1row*HID + k);
    float4 hi1 = *(const float4*)(A + (size_t)a1row*HID + k + 4);
    if (BN){
      float4 sca = *(const float4*)(coef + k);
      float4 scb = *(const float4*)(coef + k + 4);
      float4 sha = *(const float4*)(coef + 128 + k);
      float4 shb = *(const float4*)(coef + 128 + k + 4);
      lo0.x = fmaxf(fmaf(lo0.x, sca.x, sha.x), 0.f);
      lo0.y = fmaxf(fmaf(lo0.y, sca.y, sha.y), 0.f);
      lo0.z = fmaxf(fmaf(lo0.z, sca.z, sha.z), 0.f);
      lo0.w = fmaxf(fmaf(lo0.w, sca.w, sha.w), 0.f);
      hi0.x = fmaxf(fmaf(hi0.x, scb.x, shb.x), 0.f);
      hi0.y = fmaxf(fmaf(hi0.y, scb.y, shb.y), 0.f);
      hi0.z = fmaxf(fmaf(hi0.z, scb.z, shb.z), 0.f);
      hi0.w = fmaxf(fmaf(hi0.w, scb.w, shb.w), 0.f);
      lo1.x = fmaxf(fmaf(lo1.x, sca.x, sha.x), 0.f);
      lo1.y = fmaxf(fmaf(lo1.y, sca.y, sha.y), 0.f);
      lo1.z = fmaxf(fmaf(lo1.z, sca.z, sha.z), 0.f);
      lo1.w = fmaxf(fmaf(lo1.w, sca.w, sha.w), 0.f);
      hi1.x = fmaxf(fmaf(hi1.x, scb.x, shb.x), 0.f);
      hi1.y = fmaxf(fmaf(hi1.y, scb.y, shb.y), 0.f);
      hi1.z = fmaxf(fmaf(hi1.z, scb.z, shb.z), 0.f);
      hi1.w = fmaxf(fmaf(hi1.w, scb.w, shb.w), 0.f);
    }
    union { bf16x8 v; uint2 u[2]; } a0c, a1c;
    a0c.u[0] = pack_bf16x4(lo0); a0c.u[1] = pack_bf16x4(hi0);
    a1c.u[0] = pack_bf16x4(lo1); a1c.u[1] = pack_bf16x4(hi1);
    bf16x8 a0 = a0c.v, a1 = a1c.v;
    #pragma unroll
    for (int ct = 0; ct < 8; ++ct){
      int col = ct*16 + l16;
      bf16x8 b = *(bf16x8*)&WT[col*128 + (k ^ ((col&7)<<3))];
      acc[0][ct] = __builtin_amdgcn_mfma_f32_16x16x32_bf16(a0, b, acc[0][ct], 0,0,0);
      acc[1][ct] = __builtin_amdgcn_mfma_f32_16x16x32_bf16(a1, b, acc[1][ct], 0,0,0);
    }
  }

  // D: row = 4*kg + r (within tile), col = ct*16 + l16. Pair col c (even lane)
  // with c+1 (odd lane) via shfl_xor -> one uint (2 bf16) store per even lane.
  #pragma unroll
  for (int rt = 0; rt < 2; ++rt){
    int growb = row_base + rt*16 + kg*4;
    #pragma unroll
    for (int ct = 0; ct < 8; ++ct){
      #pragma unroll
      for (int r = 0; r < 4; ++r){
        float v = acc[rt][ct][r];
        float o = __shfl_xor(v, 1);
        if (!(lane & 1)){
          int grow = growb + r;
          if (grow < n){
            __hip_bfloat162 p2 = __float22bfloat162_rn({v, o});
            C[(size_t)grow*64 + ct*8 + (l16 >> 1)] = *(unsigned int*)&p2;
          }
        }
      }
    }
  }
}

// ---------------- gather / BN / final ----------------

static __device__ inline float2 bf16pair(unsigned int u){
  __hip_bfloat162 h = *(__hip_bfloat162*)&u;
  return __bfloat1622float2(h);
}

// out[node][:] = bias + dinv^2 * xw[node][:] + sum_j w_j * xw[src_j][:]
// One wave per node, 2 bf16 channels per lane, 4x unrolled (MLP).
__global__ __launch_bounds__(256) void k_gather128(const unsigned int* __restrict__ xwb,
    const int2* __restrict__ csr,
    const int* __restrict__ rowptr, const int* __restrict__ cnt,
    const float* __restrict__ dinv, const float* __restrict__ bias,
    float* __restrict__ out, int n){
  int node = blockIdx.x*4 + (threadIdx.x >> 6);
  int lane = threadIdx.x & 63;
  if (node >= n) return;
  int j = rowptr[node];
  int m = cnt[node];
  int end = j + m;
  float di = dinv[node];
  float2 b = *(const float2*)(bias + lane*2);
  float2 self = bf16pair(xwb[(size_t)node*64 + lane]);
  float sw = di * di;
  float accx = fmaf(sw, self.x, b.x);
  float accy = fmaf(sw, self.y, b.y);
  for (; j + 4 <= end; j += 4){
    int2 e0 = csr[j+0], e1 = csr[j+1], e2 = csr[j+2], e3 = csr[j+3];
    unsigned int u0 = xwb[(size_t)e0.x*64 + lane];
    unsigned int u1 = xwb[(size_t)e1.x*64 + lane];
    unsigned int u2 = xwb[(size_t)e2.x*64 + lane];
    unsigned int u3 = xwb[(size_t)e3.x*64 + lane];
    float2 v0 = bf16pair(u0), v1 = bf16pair(u1), v2 = bf16pair(u2), v3 = bf16pair(u3);
    float w0 = __int_as_float(e0.y), w1 = __int_as_float(e1.y);
    float w2 = __int_as_float(e2.y), w3 = __int_as_float(e3.y);
    accx = fmaf(w0, v0.x, accx); accy = fmaf(w0, v0.y, accy);
    accx = fmaf(w1, v1.x, accx); accy = fmaf(w1, v1.y, accy);
    accx = fmaf(w2, v2.x, accx); accy = fmaf(w2, v2.y, accy);
    accx = fmaf(w3, v3.x, accx); accy = fmaf(w3, v3.y, accy);
  }
  if (j + 2 <= end){
    int2 e0 = csr[j+0], e1 = csr[j+1];
    unsigned int u0 = xwb[(size_t)e0.x*64 + lane];
    unsigned int u1 = xwb[(size_t)e1.x*64 + lane];
    float2 v0 = bf16pair(u0), v1 = bf16pair(u1);
    float w0 = __int_as_float(e0.y), w1 = __int_as_float(e1.y);
    accx = fmaf(w0, v0.x, accx); accy = fmaf(w0, v0.y, accy);
    accx = fmaf(w1, v1.x, accx); accy = fmaf(w1, v1.y, accy);
    j += 2;
  }
  if (j < end){
    int2 e0 = csr[j];
    float2 v0 = bf16pair(xwb[(size_t)e0.x*64 + lane]);
    float w0 = __int_as_float(e0.y);
    accx = fmaf(w0, v0.x, accx); accy = fmaf(w0, v0.y, accy);
  }
  float2 r; r.x = accx; r.y = accy;
  *(float2*)(out + (size_t)node*HID + lane*2) = r;
}

__global__ __launch_bounds__(256) void k_bnstats(const float* __restrict__ h,
                                                 float* stats, int n){
  __shared__ float ls[256], lq[256];
  int c = threadIdx.x & 127;
  int r0 = blockIdx.x*2 + (threadIdx.x >> 7);
  float s = 0.f, q = 0.f;
  for (int r = r0; r < n; r += gridDim.x*2){
    float v = h[(size_t)r*HID + c];
    s += v;
    q = fmaf(v, v, q);
  }
  ls[threadIdx.x] = s; lq[threadIdx.x] = q;
  __syncthreads();
  if (threadIdx.x < 128){
    s = ls[threadIdx.x] + ls[threadIdx.x + 128];
    q = lq[threadIdx.x] + lq[threadIdx.x + 128];
    atomicAdd(&stats[c], s);
    atomicAdd(&stats[128 + c], q);
  }
}

__global__ void k_bnfin(const float* __restrict__ stats, const float* __restrict__ gamma,
                        const float* __restrict__ beta, float* coef, int n){
  int c = threadIdx.x;  // 128 threads
  float inv_n = 1.0f / (float)n;
  float mean = stats[c] * inv_n;
  float var = fmaxf(stats[128 + c] * inv_n - mean*mean, 0.f);
  float sc = gamma[c] / sqrtf(var + BN_EPS);
  coef[c] = sc;
  coef[128 + c] = fmaf(-mean, sc, beta[c]);
}

__global__ __launch_bounds__(256) void k_dotW3(const float* __restrict__ h,
    const float* __restrict__ coef, const float* __restrict__ W3,
    float* __restrict__ xw3, int n){
  int lane = threadIdx.x & 31;
  int row = blockIdx.x*8 + (threadIdx.x >> 5);
  if (row >= n) return;
  float4 v  = *(const float4*)(h + (size_t)row*HID + lane*4);
  float4 sc = *(const float4*)(coef + lane*4);
  float4 sh = *(const float4*)(coef + 128 + lane*4);
  float4 w  = *(const float4*)(W3 + lane*4);
  float acc = fmaxf(fmaf(v.x, sc.x, sh.x), 0.f) * w.x
            + fmaxf(fmaf(v.y, sc.y, sh.y), 0.f) * w.y
            + fmaxf(fmaf(v.z, sc.z, sh.z), 0.f) * w.z
            + fmaxf(fmaf(v.w, sc.w, sh.w), 0.f) * w.w;
  #pragma unroll
  for (int m = 1; m < 32; m <<= 1) acc += __shfl_xor(acc, m, 32);
  if (lane == 0) xw3[row] = acc;
}

__global__ void k_gather1(const float* __restrict__ xw3, const int2* __restrict__ csr,
    const int* __restrict__ rowptr,
    const int* __restrict__ cnt, const float* __restrict__ dinv,
    const float* __restrict__ b3, float* __restrict__ out, int n){
  int i = blockIdx.x*256 + threadIdx.x;
  if (i >= n) return;
  float di = dinv[i];
  float acc = fmaf(di*di, xw3[i], b3[0]);
  int s = rowptr[i], m = cnt[i];
  for (int j = 0; j < m; ++j){
    int2 e = csr[s + j];
    acc = fmaf(__int_as_float(e.y), xw3[e.x], acc);
  }
  out[i] = acc;
}

extern "C" void kernel_launch(void* const* d_in, const int* in_sizes, int n_in,
                              void* d_out, int out_size, void* d_ws, size_t ws_size,
                              hipStream_t stream){
  const float* x    = (const float*)d_in[0];
  const int*   ei   = (const int*)  d_in[1];
  const float* attr = (const float*)d_in[2];
  const float* W1   = (const float*)d_in[3];
  const float* b1   = (const float*)d_in[4];
  const float* g1   = (const float*)d_in[5];
  const float* be1  = (const float*)d_in[6];
  const float* W2   = (const float*)d_in[7];
  const float* b2   = (const float*)d_in[8];
  const float* g2   = (const float*)d_in[9];
  const float* be2  = (const float*)d_in[10];
  const float* W3   = (const float*)d_in[11];
  const float* b3   = (const float*)d_in[12];
  float* out = (float*)d_out;

  const int N = in_sizes[0] / HID;   // 100000
  const int E = in_sizes[2];         // 1600000

  char* w = (char*)d_ws;
  auto take = [&](size_t bytes) -> char* { char* p = w; w += alignup(bytes); return p; };
  unsigned long long* hist = (unsigned long long*)take((size_t)8*N*8);
  int*   cursorR= (int*)  take((size_t)8*N*4);
  float* dinv   = (float*)take((size_t)N*4);
  int*   cnt    = (int*)  take((size_t)N*4);
  int*   rowptr = (int*)  take((size_t)N*4);
  int*   bsum   = (int*)  take(512*4);
  float* stats  = (float*)take(256*4);
  float* coef1  = (float*)take(256*4);
  float* coef2  = (float*)take(256*4);
  int2*  csr    = (int2*) take((size_t)E*8);
  float* xw3    = (float*)take((size_t)N*4);
  unsigned int* bufA = (unsigned int*)take((size_t)N*64*4);  // bf16 pairs [N,64]
  float* bufB   = (float*)take((size_t)N*HID*4);
  (void)ws_size; (void)n_in; (void)out_size;

  int nbN = (N + 255)/256;   // 391
  int nbE = (E + 255)/256;   // 6250
  int nbG = (N + 127)/128;   // 782 gemm blocks

  // graph preprocessing
  hipMemsetAsync(hist, 0, (size_t)8*N*8, stream);
  k_edge_pass1R <<<nbE, 256, 0, stream>>>(ei, attr, hist, N, E);
  k_degcnt      <<<nbN, 256, 0, stream>>>(hist, dinv, cnt, N);
  k_scanA       <<<nbN, 256, 0, stream>>>(cnt, rowptr, bsum, N);
  k_scanB       <<<1,   512, 0, stream>>>(bsum, nbN);
  k_scanC_cursor<<<nbN, 256, 0, stream>>>(rowptr, bsum, hist, cursorR, N);
  k_fill        <<<nbE, 256, 0, stream>>>(ei, attr, dinv, cursorR, csr, N, E);

  // layer 1
  k_gemm_mfma<false><<<nbG, 256, 0, stream>>>(x, W1, nullptr, bufA, N);
  k_gather128       <<<(N+3)/4, 256, 0, stream>>>(bufA, csr, rowptr, cnt, dinv, b1, bufB, N);
  hipMemsetAsync(stats, 0, 256*4, stream);
  k_bnstats         <<<512, 256, 0, stream>>>(bufB, stats, N);
  k_bnfin           <<<1, 128, 0, stream>>>(stats, g1, be1, coef1, N);

  // layer 2 (BN1+ReLU fused into gemm A-load)
  k_gemm_mfma<true> <<<nbG, 256, 0, stream>>>(bufB, W2, coef1, bufA, N);
  k_gather128       <<<(N+3)/4, 256, 0, stream>>>(bufA, csr, rowptr, cnt, dinv, b2, bufB, N);
  hipMemsetAsync(stats, 0, 256*4, stream);
  k_bnstats         <<<512, 256, 0, stream>>>(bufB, stats, N);
  k_bnfin           <<<1, 128, 0, stream>>>(stats, g2, be2, coef2, N);

  // layer 3 (BN2+ReLU fused into the 128->1 dot)
  k_dotW3           <<<(N+7)/8, 256, 0, stream>>>(bufB, coef2, W3, xw3, N);
  k_gather1         <<<nbN, 256, 0, stream>>>(xw3, csr, rowptr, cnt, dinv, b3, out, N);
}